// Round 5
// baseline (2113.122 us; speedup 1.0000x reference)
//
#include <hip/hip_runtime.h>
#include <hip/hip_bf16.h>

// GRU forward, T=512 B=256 I=H=256 fp32 in, fp32 [B,1] out.
// v5: model fix — one wave on one SIMD gets ~16 cyc per 16x16x32 MFMA (not
// 4.85; that was the 4-SIMD/CU figure). Recurrence floor = 6144 MFMA/step on
// 16 CUs (M=16 forces >=16 batch rows/block) = 1536 cyc/step ~= 327 us.
// Design to approach it:
//  - gru_step5: 16 blocks x 256 thr (4 waves, 1/SIMD, waves_per_eu(1,1) ->
//    512-reg unified budget). FULL W_hh residency (384 regs/lane) — zero LDS
//    weight traffic. LDS/step = 8KB h-tile x4-wave broadcast + 24KB gi.
//  - gi via 6x global_load_lds per lane issued one step ahead, counted
//    s_waitcnt vmcnt(6) (never drains the in-flight next-step DMAs), into
//    wave-PRIVATE LDS (no barrier coupling). 1 barrier/step (h tile only).
//  - combine fully in-register: MFMA D-layout puts r,z,n of the same
//    (row,col) in the same lane (acc[g][ct][q]); no exchange, no divergence.
//  - gi_gemm6: exact mirror (same fragment/store layout) -> per-lane 96B
//    dense stores; 256 blocks, double-buffered x staging; HBM-bound.

#define TT 512
#define BB 256
#define II 256
#define HH 256

#define SRZ (-1.4426950408889634f)   // -log2(e): sigmoid(a) = rcp(1+exp2(SRZ*a))
#define SN  (2.8853900817779268f)    // 2*log2(e): tanh(y) = 1-2*rcp(1+exp2(SN*y))

typedef __attribute__((ext_vector_type(8))) short short8;
typedef __attribute__((ext_vector_type(4))) float f32x4;

__device__ __forceinline__ unsigned short rne_bf16(float f) {
  union { float f; unsigned u; } v; v.f = f;
  unsigned r = v.u + 0x7FFFu + ((v.u >> 16) & 1u);
  return (unsigned short)(r >> 16);
}
__device__ __forceinline__ float bf2f(unsigned short b) {
  union { unsigned u; float f; } v; v.u = ((unsigned)b) << 16;
  return v.f;
}
__device__ __forceinline__ float sigm(float x) { return 1.0f / (1.0f + __expf(-x)); }
__device__ __forceinline__ float tanhfast(float x) {
  return 1.0f - 2.0f / (__expf(2.0f * x) + 1.0f);
}

__device__ __forceinline__ short8 ldw8(const float* __restrict__ p) {
  float4 a = *reinterpret_cast<const float4*>(p);
  float4 b = *reinterpret_cast<const float4*>(p + 4);
  short8 r;
  r[0] = (short)rne_bf16(a.x); r[1] = (short)rne_bf16(a.y);
  r[2] = (short)rne_bf16(a.z); r[3] = (short)rne_bf16(a.w);
  r[4] = (short)rne_bf16(b.x); r[5] = (short)rne_bf16(b.y);
  r[6] = (short)rne_bf16(b.z); r[7] = (short)rne_bf16(b.w);
  return r;
}
__device__ __forceinline__ short8 ldw8s(const float* __restrict__ p, float s) {
  float4 a = *reinterpret_cast<const float4*>(p);
  float4 b = *reinterpret_cast<const float4*>(p + 4);
  short8 r;
  r[0] = (short)rne_bf16(a.x * s); r[1] = (short)rne_bf16(a.y * s);
  r[2] = (short)rne_bf16(a.z * s); r[3] = (short)rne_bf16(a.w * s);
  r[4] = (short)rne_bf16(b.x * s); r[5] = (short)rne_bf16(b.y * s);
  r[6] = (short)rne_bf16(b.z * s); r[7] = (short)rne_bf16(b.w * s);
  return r;
}

// 8-elem-granule XOR swizzle for [16][256] ushort tiles: keeps 16B reads
// contiguous, spreads the 16 rows of a b128 column-read across 8 bank-starts
// (2 lanes each = free).
#define SWZ8(m, k) ((m) * 256 + ((k) ^ (((m) & 7) * 8)))
// legacy 16-granule swizzle (fallback kernel)
#define SWZ(m, k) ((m) * 256 + ((k) ^ ((m) * 16)))

__device__ __forceinline__ f32x4 mfma16(short8 a, short8 b, f32x4 c) {
  return __builtin_amdgcn_mfma_f32_16x16x32_bf16(a, b, c, 0, 0, 0);
}

__device__ __forceinline__ void gload_lds16(const void* g, void* lds) {
  __builtin_amdgcn_global_load_lds(
      (const __attribute__((address_space(1))) unsigned int*)g,
      (__attribute__((address_space(3))) unsigned int*)lds, 16, 0, 0);
}

// ---------------- Phase 1: gi = scale*(x @ W_ih^T + bias), fragment layout --
// Per (x-tile, wave, lane): 48 ushorts (96 B) at
//   gi + ((tile*4 + w)*64 + l)*48, chunk (2g+cp)*8 = short8 of
//   [ct=2cp (q0..3), ct=2cp+1 (q0..3)] for gate g. r,z folded with
//   SRZ*(bih+bhh); n folded with SN*bih.
__global__ __launch_bounds__(256)
__attribute__((amdgpu_waves_per_eu(1, 1)))
void gi_gemm6(const float* __restrict__ x, const float* __restrict__ Wih,
              const float* __restrict__ bih, const float* __restrict__ bhh,
              unsigned short* __restrict__ gi, int ntiles) {
  __shared__ __align__(16) unsigned short ax[2][4096];
  const int tid = threadIdx.x, l = tid & 63, w = tid >> 6;
  const int g4 = l >> 4, i15 = l & 15;

  short8 wf[3][4][8];
  float bs[3][4];
#pragma unroll
  for (int g = 0; g < 3; ++g)
#pragma unroll
    for (int ct = 0; ct < 4; ++ct) {
      int j = 64 * w + 16 * ct + i15;
      float s = (g == 2) ? SN : SRZ;
#pragma unroll
      for (int c = 0; c < 8; ++c)
        wf[g][ct][c] = ldw8s(Wih + (size_t)(g * 256 + j) * 256 + c * 32 + g4 * 8, s);
      bs[g][ct] = (g == 2) ? SN * bih[512 + j]
                           : SRZ * (bih[g * 256 + j] + bhh[g * 256 + j]);
    }

  auto stage = [&](int buf, int t) {
#pragma unroll
    for (int p = 0; p < 4; ++p) {
      int idx = p * 256 + tid;
      int m = idx >> 6, k0 = (idx & 63) << 2;
      float4 v = *reinterpret_cast<const float4*>(x + (size_t)t * 4096 + m * 256 + k0);
      ushort4 b;
      b.x = rne_bf16(v.x); b.y = rne_bf16(v.y);
      b.z = rne_bf16(v.z); b.w = rne_bf16(v.w);
      *reinterpret_cast<ushort4*>(&ax[buf][SWZ8(m, k0)]) = b;
    }
  };

  if (blockIdx.x >= ntiles) return;
  stage(0, blockIdx.x);
  int cur = 0;
  for (int tile = blockIdx.x; tile < ntiles; tile += 256) {
    __syncthreads();
    int tn = tile + 256;
    if (tn < ntiles) stage(cur ^ 1, tn);
    f32x4 aR[4], aZ[4], aN[4];
#pragma unroll
    for (int ct = 0; ct < 4; ++ct) {
      aR[ct] = (f32x4){0, 0, 0, 0};
      aZ[ct] = (f32x4){0, 0, 0, 0};
      aN[ct] = (f32x4){0, 0, 0, 0};
    }
#pragma unroll
    for (int c = 0; c < 8; ++c) {
      short8 ah = *reinterpret_cast<const short8*>(&ax[cur][SWZ8(l & 15, c * 32 + g4 * 8)]);
#pragma unroll
      for (int ct = 0; ct < 4; ++ct) {
        aR[ct] = mfma16(ah, wf[0][ct][c], aR[ct]);
        aZ[ct] = mfma16(ah, wf[1][ct][c], aZ[ct]);
        aN[ct] = mfma16(ah, wf[2][ct][c], aN[ct]);
      }
    }
    unsigned short* gp = gi + ((size_t)tile * 4 + w) * 3072 + (size_t)l * 48;
#pragma unroll
    for (int cp = 0; cp < 2; ++cp) {
      short8 oR, oZ, oN;
#pragma unroll
      for (int tl = 0; tl < 2; ++tl) {
        int ct = 2 * cp + tl;
#pragma unroll
        for (int q = 0; q < 4; ++q) {
          oR[tl * 4 + q] = (short)rne_bf16(aR[ct][q] + bs[0][ct]);
          oZ[tl * 4 + q] = (short)rne_bf16(aZ[ct][q] + bs[1][ct]);
          oN[tl * 4 + q] = (short)rne_bf16(aN[ct][q] + bs[2][ct]);
        }
      }
      *reinterpret_cast<short8*>(gp + (0 + cp) * 8) = oR;
      *reinterpret_cast<short8*>(gp + (2 + cp) * 8) = oZ;
      *reinterpret_cast<short8*>(gp + (4 + cp) * 8) = oN;
    }
    cur ^= 1;
  }
}

// ---------------- Phase 2: persistent GRU recurrence (v5) ----------------
__global__ __launch_bounds__(256)
__attribute__((amdgpu_waves_per_eu(1, 1)))
void gru_step5(const float* __restrict__ Whh, const float* __restrict__ bhh,
               const float* __restrict__ Wout, const float* __restrict__ bout,
               const unsigned short* __restrict__ gi, float* __restrict__ hchk,
               float* __restrict__ out, int t0, int nt) {
  __shared__ __align__(16) unsigned short hbuf[2][4096];       // 16 KB (SWZ8)
  __shared__ __align__(16) unsigned short gibuf[2][4][6][512]; // 48 KB DMA dest
  const int tid = threadIdx.x, l = tid & 63, w = tid >> 6;
  const int g4 = l >> 4, i15 = l & 15;
  const int bx = blockIdx.x, b0 = bx * 16;

  // full W_hh residency: 96 short8 = 384 regs/lane
  short8 wf[3][4][8];
  float cn[4];
#pragma unroll
  for (int g = 0; g < 3; ++g)
#pragma unroll
    for (int ct = 0; ct < 4; ++ct) {
      int j = 64 * w + 16 * ct + i15;
      float s = (g == 2) ? SN : SRZ;
#pragma unroll
      for (int c = 0; c < 8; ++c)
        wf[g][ct][c] = ldw8s(Whh + (size_t)(g * 256 + j) * 256 + c * 32 + g4 * 8, s);
    }
#pragma unroll
  for (int ct = 0; ct < 4; ++ct) cn[ct] = SN * bhh[512 + 64 * w + 16 * ct + i15];

  f32x4 hv[4];
  if (t0 == 0) {
#pragma unroll
    for (int ct = 0; ct < 4; ++ct) hv[ct] = (f32x4){0, 0, 0, 0};
    for (int i = tid; i < 4096; i += 256) hbuf[0][i] = 0;
  } else {
#pragma unroll
    for (int ct = 0; ct < 4; ++ct) {
      int j = 64 * w + 16 * ct + i15;
#pragma unroll
      for (int q = 0; q < 4; ++q) {
        float val = hchk[(size_t)(b0 + 4 * g4 + q) * 256 + j];
        hv[ct][q] = val;
        hbuf[0][SWZ8(4 * g4 + q, j)] = rne_bf16(val);
      }
    }
  }
  // prologue DMA: step-0 gi into gibuf[0] (wave-private, 6 x 16B per lane)
  {
    const char* gsrc = (const char*)gi + (((size_t)bx * 4 + w) * 64 + l) * 96;
#pragma unroll
    for (int k = 0; k < 6; ++k)
      gload_lds16(gsrc + k * 16, &gibuf[0][w][k][0]);
  }
  __syncthreads();

  for (int lt = 0; lt < nt; ++lt) {
    const int cur = lt & 1, nxt = cur ^ 1;
    {  // issue next step's 6 DMAs (always 6 -> vmcnt(6) is exact)
      int tn = (lt + 1 < nt) ? lt + 1 : lt;
      const char* gsrc =
          (const char*)gi + ((((size_t)tn * 16 + bx) * 4 + w) * 64 + l) * 96;
#pragma unroll
      for (int k = 0; k < 6; ++k)
        gload_lds16(gsrc + k * 16, &gibuf[nxt][w][k][0]);
    }

    f32x4 aR[4], aZ[4], aN[4];
#pragma unroll
    for (int ct = 0; ct < 4; ++ct) {
      aR[ct] = (f32x4){0, 0, 0, 0};
      aZ[ct] = (f32x4){0, 0, 0, 0};
      aN[ct] = (f32x4){0, 0, 0, 0};
    }
    const unsigned short* hb = hbuf[cur];
#pragma unroll
    for (int c = 0; c < 8; ++c) {
      short8 ah = *reinterpret_cast<const short8*>(&hb[SWZ8(l & 15, c * 32 + g4 * 8)]);
#pragma unroll
      for (int ct = 0; ct < 4; ++ct) {
        aR[ct] = mfma16(ah, wf[0][ct][c], aR[ct]);
        aZ[ct] = mfma16(ah, wf[1][ct][c], aZ[ct]);
        aN[ct] = mfma16(ah, wf[2][ct][c], aN[ct]);
      }
    }

    // wait for THIS step's DMA only (6 newest = next step's, stay in flight)
    asm volatile("s_waitcnt vmcnt(6)" ::: "memory");

    unsigned short* hw = hbuf[nxt];
#pragma unroll
    for (int cp = 0; cp < 2; ++cp) {
      short8 gR = *reinterpret_cast<const short8*>(&gibuf[cur][w][0 + cp][l * 8]);
      short8 gZ = *reinterpret_cast<const short8*>(&gibuf[cur][w][2 + cp][l * 8]);
      short8 gN = *reinterpret_cast<const short8*>(&gibuf[cur][w][4 + cp][l * 8]);
#pragma unroll
      for (int tl = 0; tl < 2; ++tl) {
        int ct = 2 * cp + tl;
#pragma unroll
        for (int q = 0; q < 4; ++q) {
          float rr = __builtin_amdgcn_rcpf(
              1.0f + __builtin_amdgcn_exp2f(aR[ct][q] + bf2f((unsigned short)gR[tl * 4 + q])));
          float zz = __builtin_amdgcn_rcpf(
              1.0f + __builtin_amdgcn_exp2f(aZ[ct][q] + bf2f((unsigned short)gZ[tl * 4 + q])));
          float y = bf2f((unsigned short)gN[tl * 4 + q]) + rr * (aN[ct][q] + cn[ct]);
          float nn = 1.0f - 2.0f * __builtin_amdgcn_rcpf(1.0f + __builtin_amdgcn_exp2f(y));
          float hq = nn + zz * (hv[ct][q] - nn);
          hv[ct][q] = hq;
          hw[SWZ8(4 * g4 + q, 64 * w + 16 * ct + i15)] = rne_bf16(hq);
        }
      }
    }
    __syncthreads();
  }

  asm volatile("s_waitcnt vmcnt(0)" ::: "memory");  // drain last dummy DMAs
  if (t0 + nt < TT) {
#pragma unroll
    for (int ct = 0; ct < 4; ++ct) {
      int j = 64 * w + 16 * ct + i15;
#pragma unroll
      for (int q = 0; q < 4; ++q)
        hchk[(size_t)(b0 + 4 * g4 + q) * 256 + j] = hv[ct][q];
    }
  } else {
    float* hfin = (float*)&gibuf[0][0][0][0];  // 16 KB overlay (DMA drained)
    __syncthreads();
#pragma unroll
    for (int ct = 0; ct < 4; ++ct) {
      int j = 64 * w + 16 * ct + i15;
#pragma unroll
      for (int q = 0; q < 4; ++q)
        hfin[(4 * g4 + q) * 256 + j] = hv[ct][q];
    }
    __syncthreads();
#pragma unroll
    for (int q2 = 0; q2 < 4; ++q2) {
      int r = 4 * w + q2;
      float s = 0.0f;
#pragma unroll
      for (int k = 0; k < 4; ++k) {
        int col = l + 64 * k;
        s += hfin[r * 256 + col] * Wout[col];
      }
#pragma unroll
      for (int off = 32; off > 0; off >>= 1) s += __shfl_xor(s, off, 64);
      if (l == 0) out[b0 + r] = sigm(s + bout[0]);
    }
  }
}

// ---------------- Fused fallback (used only if ws too small) ------------
__global__ __launch_bounds__(1024, 1) void gru_fused_legacy(
    const float* __restrict__ x, const float* __restrict__ Wih,
    const float* __restrict__ Whh, const float* __restrict__ bih,
    const float* __restrict__ bhh, const float* __restrict__ Wout,
    const float* __restrict__ bout, float* __restrict__ out) {
  __shared__ unsigned short hbuf[2][16 * 256];
  __shared__ unsigned short xbuf[2][16 * 256];
  __shared__ float hfin[16][256];
  int tid = threadIdx.x, lane = tid & 63, w = tid >> 6;
  int i15 = lane & 15, g4 = lane >> 4;
  int b0 = blockIdx.x * 16;
  int j = 16 * w + i15;

  short8 whh0[8], whh1[8], whh2[8], wih0[8], wih1[8], wih2[8];
#pragma unroll
  for (int c = 0; c < 8; ++c) {
    int ko = c * 32 + g4 * 8;
    whh0[c] = ldw8(Whh + (size_t)j * 256 + ko);
    whh1[c] = ldw8(Whh + (size_t)(256 + j) * 256 + ko);
    whh2[c] = ldw8(Whh + (size_t)(512 + j) * 256 + ko);
    wih0[c] = ldw8(Wih + (size_t)j * 256 + ko);
    wih1[c] = ldw8(Wih + (size_t)(256 + j) * 256 + ko);
    wih2[c] = ldw8(Wih + (size_t)(512 + j) * 256 + ko);
  }
  float bias_r = bih[j] + bhh[j];
  float bias_z = bih[256 + j] + bhh[256 + j];
  float bihn = bih[512 + j], bhhn = bhh[512 + j];

  f32x4 h = {0, 0, 0, 0};
  for (int idx = tid; idx < 16 * 256; idx += 1024) hbuf[0][idx] = 0;
  {
    int m = tid >> 6, k0 = (tid & 63) << 2;
    float4 v = *reinterpret_cast<const float4*>(x + (size_t)b0 * II + m * 256 + k0);
    ushort4 b;
    b.x = rne_bf16(v.x); b.y = rne_bf16(v.y);
    b.z = rne_bf16(v.z); b.w = rne_bf16(v.w);
    *reinterpret_cast<ushort4*>(&xbuf[0][SWZ(m, k0)]) = b;
  }
  __syncthreads();

  for (int lt = 0; lt < TT; ++lt) {
    int cur = lt & 1, nxt = cur ^ 1;
    short8 ah[8], axf[8];
#pragma unroll
    for (int c = 0; c < 8; ++c) {
      int m = lane & 15, k0 = c * 32 + g4 * 8;
      ah[c] = *reinterpret_cast<const short8*>(&hbuf[cur][SWZ(m, k0)]);
      axf[c] = *reinterpret_cast<const short8*>(&xbuf[cur][SWZ(m, k0)]);
    }
    f32x4 gr = {0, 0, 0, 0}, gz = {0, 0, 0, 0}, gn = {0, 0, 0, 0};
    f32x4 ar = {0, 0, 0, 0}, az = {0, 0, 0, 0}, an = {0, 0, 0, 0};
#pragma unroll
    for (int c = 0; c < 8; ++c) {
      gr = mfma16(axf[c], wih0[c], gr);
      gz = mfma16(axf[c], wih1[c], gz);
      gn = mfma16(axf[c], wih2[c], gn);
    }
    if (lt + 1 < TT) {
      int m = tid >> 6, k0 = (tid & 63) << 2;
      float4 v = *reinterpret_cast<const float4*>(
          x + ((size_t)(lt + 1) * BB + b0) * II + m * 256 + k0);
      ushort4 b;
      b.x = rne_bf16(v.x); b.y = rne_bf16(v.y);
      b.z = rne_bf16(v.z); b.w = rne_bf16(v.w);
      *reinterpret_cast<ushort4*>(&xbuf[nxt][SWZ(m, k0)]) = b;
    }
#pragma unroll
    for (int c = 0; c < 8; ++c) {
      ar = mfma16(ah[c], whh0[c], ar);
      az = mfma16(ah[c], whh1[c], az);
      an = mfma16(ah[c], whh2[c], an);
    }
#pragma unroll
    for (int q = 0; q < 4; ++q) {
      float r = sigm(ar[q] + gr[q] + bias_r);
      float zz = sigm(az[q] + gz[q] + bias_z);
      float nn = tanhfast(gn[q] + bihn + r * (an[q] + bhhn));
      float hq = (1.0f - zz) * nn + zz * h[q];
      h[q] = hq;
      hbuf[nxt][SWZ(g4 * 4 + q, j)] = rne_bf16(hq);
    }
    __syncthreads();
  }
#pragma unroll
  for (int q = 0; q < 4; ++q) hfin[g4 * 4 + q][j] = h[q];
  __syncthreads();
  float s = 0.0f;
#pragma unroll
  for (int i = 0; i < 4; ++i) {
    int k = lane + 64 * i;
    s += hfin[w][k] * Wout[k];
  }
#pragma unroll
  for (int off = 32; off > 0; off >>= 1) s += __shfl_xor(s, off, 64);
  if (lane == 0) out[b0 + w] = sigm(s + bout[0]);
}

extern "C" void kernel_launch(void* const* d_in, const int* in_sizes, int n_in,
                              void* d_out, int out_size, void* d_ws, size_t ws_size,
                              hipStream_t stream) {
  const float* x    = (const float*)d_in[0];
  const float* Wih  = (const float*)d_in[1];
  const float* Whh  = (const float*)d_in[2];
  const float* bih  = (const float*)d_in[3];
  const float* bhh  = (const float*)d_in[4];
  const float* Wout = (const float*)d_in[5];
  const float* bout = (const float*)d_in[6];
  float* out = (float*)d_out;

  const size_t HBYTES = (size_t)BB * HH * sizeof(float);  // 256 KB h checkpoint
  const size_t STEP_BYTES = (size_t)16 * 4 * 64 * 96;     // 384 KB gi per step
  size_t gi_cap = ws_size > HBYTES ? ws_size - HBYTES : 0;
  long tc = (long)(gi_cap / STEP_BYTES);
  if (tc > TT) tc = TT;

  if (tc >= 32) {
    float* hchk = (float*)d_ws;
    unsigned short* gi = (unsigned short*)((char*)d_ws + HBYTES);
    for (int t0 = 0; t0 < TT; t0 += (int)tc) {
      int nt = (TT - t0) < (int)tc ? (TT - t0) : (int)tc;
      gi_gemm6<<<dim3(256), dim3(256), 0, stream>>>(
          x + (size_t)t0 * BB * II, Wih, bih, bhh, gi, nt * 16);
      gru_step5<<<dim3(16), dim3(256), 0, stream>>>(
          Whh, bhh, Wout, bout, gi, hchk, out, t0, nt);
    }
  } else {
    gru_fused_legacy<<<dim3(16), dim3(1024), 0, stream>>>(
        x, Wih, Whh, bih, bhh, Wout, bout, out);
  }
}

// Round 6
// 1317.793 us; speedup vs baseline: 1.6035x; 1.6035x over previous
//
#include <hip/hip_runtime.h>
#include <hip/hip_bf16.h>

// GRU forward, T=512 B=256 I=H=256 fp32 in, fp32 [B,1] out.
// v6 = v2's proven structure (16 blocks x 512 thr, 2 waves/SIMD) with its one
// big per-step cost removed:
//  - ALL W_hh weights register-resident: wave owns H-cols [32w,32w+32) for all
//    3 gates = 48 short8 = 192 regs/lane (unified budget 256 at 2 waves/EU).
//    No LDS weight streaming (v2 spent ~1500 cyc/step on the n-gate stream).
//  - gi: per-lane 48B contiguous -> 3x global_load_dwordx4 (imm offsets) from
//    one pointer stepped by +384KB/step. Issued at loop top, consumed after
//    the MFMA block -> L3/HBM latency hidden under ~1900 cyc of MFMA; loads
//    are consumed before the barrier so the compiler's vmcnt(0)-before-
//    s_barrier drain is free. NO global_load_lds, NO cross-step prefetch
//    (v3/v5 lesson: barrier drains kill deep prefetch at HIP level).
//  - register diet vs v3 (which spilled): no gibuf machinery, no goff arrays.
//    Working set ~= 192 wf + 24 acc + 12 gi + 8 h + ~20 misc ~= 252 <= 256.
//  - combine fully in-register (D-layout gives r,z,n of same (row,col) in the
//    same lane); exp2 scaling folded into weights/biases at init.

#define TT 512
#define BB 256
#define II 256
#define HH 256

#define SRZ (-1.4426950408889634f)   // -log2(e): sigmoid(a) = rcp(1+exp2(SRZ*a))
#define SN  (2.8853900817779268f)    // 2*log2(e): tanh(y) = 1-2*rcp(1+exp2(SN*y))

typedef __attribute__((ext_vector_type(8))) short short8;
typedef __attribute__((ext_vector_type(4))) float f32x4;

__device__ __forceinline__ unsigned short rne_bf16(float f) {
  union { float f; unsigned u; } v; v.f = f;
  unsigned r = v.u + 0x7FFFu + ((v.u >> 16) & 1u);
  return (unsigned short)(r >> 16);
}
__device__ __forceinline__ float bf2f(unsigned short b) {
  union { unsigned u; float f; } v; v.u = ((unsigned)b) << 16;
  return v.f;
}
__device__ __forceinline__ float sigm(float x) { return 1.0f / (1.0f + __expf(-x)); }
__device__ __forceinline__ float tanhfast(float x) {
  return 1.0f - 2.0f / (__expf(2.0f * x) + 1.0f);
}

__device__ __forceinline__ short8 ldw8(const float* __restrict__ p) {
  float4 a = *reinterpret_cast<const float4*>(p);
  float4 b = *reinterpret_cast<const float4*>(p + 4);
  short8 r;
  r[0] = (short)rne_bf16(a.x); r[1] = (short)rne_bf16(a.y);
  r[2] = (short)rne_bf16(a.z); r[3] = (short)rne_bf16(a.w);
  r[4] = (short)rne_bf16(b.x); r[5] = (short)rne_bf16(b.y);
  r[6] = (short)rne_bf16(b.z); r[7] = (short)rne_bf16(b.w);
  return r;
}
__device__ __forceinline__ short8 ldw8s(const float* __restrict__ p, float s) {
  float4 a = *reinterpret_cast<const float4*>(p);
  float4 b = *reinterpret_cast<const float4*>(p + 4);
  short8 r;
  r[0] = (short)rne_bf16(a.x * s); r[1] = (short)rne_bf16(a.y * s);
  r[2] = (short)rne_bf16(a.z * s); r[3] = (short)rne_bf16(a.w * s);
  r[4] = (short)rne_bf16(b.x * s); r[5] = (short)rne_bf16(b.y * s);
  r[6] = (short)rne_bf16(b.z * s); r[7] = (short)rne_bf16(b.w * s);
  return r;
}

// 8-elem-granule XOR swizzle for [16][256] ushort tiles: 16B reads stay
// contiguous; rows m and m+8 alias (2-way = free per m136).
#define SWZ8(m, k) ((m) * 256 + ((k) ^ (((m) & 7) * 8)))
// legacy 16-granule swizzle (fallback kernel only)
#define SWZ(m, k) ((m) * 256 + ((k) ^ ((m) * 16)))

__device__ __forceinline__ f32x4 mfma16(short8 a, short8 b, f32x4 c) {
  return __builtin_amdgcn_mfma_f32_16x16x32_bf16(a, b, c, 0, 0, 0);
}

// ---------------- Phase 1: gi = scale*(x @ W_ih^T + bias) -------------------
// gi ushort layout: ((tile*8 + w)*64 + l)*24 + g*8 + ct*4 + q, tile = t*16+bx.
// Each lane's 24 ushorts (48B) are contiguous -> gru does 3 dwordx4 loads.
// r,z folded with SRZ*(bih+bhh); n folded with SN*bih (bhh_n multiplies by r
// inside the gru).
__global__ __launch_bounds__(512)
__attribute__((amdgpu_waves_per_eu(2, 2)))
void gi_gemm7(const float* __restrict__ x, const float* __restrict__ Wih,
              const float* __restrict__ bih, const float* __restrict__ bhh,
              unsigned short* __restrict__ gi, int ntiles) {
  __shared__ __align__(16) unsigned short ax[2][4096];
  const int tid = threadIdx.x, l = tid & 63, w = tid >> 6;
  const int g4 = l >> 4, i15 = l & 15;

  // wave w owns H-cols [32w, 32w+32): 3 gates x 2 col-tiles x 8 chunks = 192 regs
  short8 wf[3][2][8];
  float bs[3][2];
#pragma unroll
  for (int g = 0; g < 3; ++g)
#pragma unroll
    for (int ct = 0; ct < 2; ++ct) {
      int j = 32 * w + 16 * ct + i15;
      float s = (g == 2) ? SN : SRZ;
#pragma unroll
      for (int c = 0; c < 8; ++c)
        wf[g][ct][c] = ldw8s(Wih + (size_t)(g * 256 + j) * 256 + c * 32 + g4 * 8, s);
      bs[g][ct] = (g == 2) ? SN * bih[512 + j]
                           : SRZ * (bih[g * 256 + j] + bhh[g * 256 + j]);
    }

  auto stage = [&](int buf, int t) {
#pragma unroll
    for (int p = 0; p < 2; ++p) {
      int idx = p * 512 + tid;
      int m = idx >> 6, k0 = (idx & 63) << 2;
      float4 v = *reinterpret_cast<const float4*>(x + (size_t)t * 4096 + m * 256 + k0);
      ushort4 b;
      b.x = rne_bf16(v.x); b.y = rne_bf16(v.y);
      b.z = rne_bf16(v.z); b.w = rne_bf16(v.w);
      *reinterpret_cast<ushort4*>(&ax[buf][SWZ8(m, k0)]) = b;
    }
  };

  if (blockIdx.x >= ntiles) return;
  stage(0, blockIdx.x);
  int cur = 0;
  for (int tile = blockIdx.x; tile < ntiles; tile += 256) {
    __syncthreads();
    int tn = tile + 256;
    if (tn < ntiles) stage(cur ^ 1, tn);
    f32x4 aR[2], aZ[2], aN[2];
#pragma unroll
    for (int ct = 0; ct < 2; ++ct) {
      aR[ct] = (f32x4){0, 0, 0, 0};
      aZ[ct] = (f32x4){0, 0, 0, 0};
      aN[ct] = (f32x4){0, 0, 0, 0};
    }
#pragma unroll
    for (int c = 0; c < 8; ++c) {
      short8 ah = *reinterpret_cast<const short8*>(&ax[cur][SWZ8(l & 15, c * 32 + g4 * 8)]);
#pragma unroll
      for (int ct = 0; ct < 2; ++ct) {
        aR[ct] = mfma16(ah, wf[0][ct][c], aR[ct]);
        aZ[ct] = mfma16(ah, wf[1][ct][c], aZ[ct]);
        aN[ct] = mfma16(ah, wf[2][ct][c], aN[ct]);
      }
    }
    unsigned short* gp = gi + ((size_t)tile * 512 + (size_t)(w * 64 + l)) * 24;
    short8 oR, oZ, oN;
#pragma unroll
    for (int ct = 0; ct < 2; ++ct)
#pragma unroll
      for (int q = 0; q < 4; ++q) {
        oR[ct * 4 + q] = (short)rne_bf16(aR[ct][q] + bs[0][ct]);
        oZ[ct * 4 + q] = (short)rne_bf16(aZ[ct][q] + bs[1][ct]);
        oN[ct * 4 + q] = (short)rne_bf16(aN[ct][q] + bs[2][ct]);
      }
    *reinterpret_cast<short8*>(gp) = oR;
    *reinterpret_cast<short8*>(gp + 8) = oZ;
    *reinterpret_cast<short8*>(gp + 16) = oN;
    cur ^= 1;
  }
}

// ---------------- Phase 2: persistent GRU recurrence (v6) ----------------
__global__ __launch_bounds__(512)
__attribute__((amdgpu_waves_per_eu(2, 2)))
void gru_step6(const float* __restrict__ Whh, const float* __restrict__ bhh,
               const float* __restrict__ Wout, const float* __restrict__ bout,
               const unsigned short* __restrict__ gi, float* __restrict__ hchk,
               float* __restrict__ out, int t0, int nt) {
  __shared__ __align__(16) unsigned short hbuf[2][4096];  // 16 KB (SWZ8, dbuf)
  __shared__ float hfin[16][256];                         // 16 KB (epilogue)
  const int tid = threadIdx.x, l = tid & 63, w = tid >> 6;
  const int g4 = l >> 4, i15 = l & 15;
  const int bx = blockIdx.x, b0 = bx * 16;

  // full W_hh residency: 48 short8 = 192 regs/lane
  short8 wf[3][2][8];
  float cn[2];
#pragma unroll
  for (int g = 0; g < 3; ++g)
#pragma unroll
    for (int ct = 0; ct < 2; ++ct) {
      int j = 32 * w + 16 * ct + i15;
      float s = (g == 2) ? SN : SRZ;
#pragma unroll
      for (int c = 0; c < 8; ++c)
        wf[g][ct][c] = ldw8s(Whh + (size_t)(g * 256 + j) * 256 + c * 32 + g4 * 8, s);
    }
#pragma unroll
  for (int ct = 0; ct < 2; ++ct) cn[ct] = SN * bhh[512 + 32 * w + 16 * ct + i15];

  f32x4 hv[2];
  if (t0 == 0) {
#pragma unroll
    for (int ct = 0; ct < 2; ++ct) hv[ct] = (f32x4){0, 0, 0, 0};
    for (int i = tid; i < 4096; i += 512) hbuf[0][i] = 0;
  } else {
#pragma unroll
    for (int ct = 0; ct < 2; ++ct) {
      int j = 32 * w + 16 * ct + i15;
#pragma unroll
      for (int q = 0; q < 4; ++q) {
        float val = hchk[(size_t)(b0 + 4 * g4 + q) * 256 + j];
        hv[ct][q] = val;
        hbuf[0][SWZ8(4 * g4 + q, j)] = rne_bf16(val);
      }
    }
  }
  // per-lane gi pointer; +196608 ushorts (=384KB) per step
  const unsigned short* gp = gi + ((size_t)(bx * 8 + w) * 64 + l) * 24;
  __syncthreads();

  for (int lt = 0; lt < nt; ++lt) {
    const int cur = lt & 1, nxt = cur ^ 1;
    // this step's gi: 3 dwordx4, issued now, consumed after the MFMA block
    short8 gR = *reinterpret_cast<const short8*>(gp);
    short8 gZ = *reinterpret_cast<const short8*>(gp + 8);
    short8 gN = *reinterpret_cast<const short8*>(gp + 16);

    f32x4 aR[2], aZ[2], aN[2];
#pragma unroll
    for (int ct = 0; ct < 2; ++ct) {
      aR[ct] = (f32x4){0, 0, 0, 0};
      aZ[ct] = (f32x4){0, 0, 0, 0};
      aN[ct] = (f32x4){0, 0, 0, 0};
    }
    const unsigned short* hb = hbuf[cur];
#pragma unroll
    for (int c = 0; c < 8; ++c) {
      short8 ah = *reinterpret_cast<const short8*>(&hb[SWZ8(l & 15, c * 32 + g4 * 8)]);
#pragma unroll
      for (int ct = 0; ct < 2; ++ct) {
        aR[ct] = mfma16(ah, wf[0][ct][c], aR[ct]);
        aZ[ct] = mfma16(ah, wf[1][ct][c], aZ[ct]);
        aN[ct] = mfma16(ah, wf[2][ct][c], aN[ct]);
      }
    }

    unsigned short* hw = hbuf[nxt];
#pragma unroll
    for (int ct = 0; ct < 2; ++ct) {
      int j = 32 * w + 16 * ct + i15;
#pragma unroll
      for (int q = 0; q < 4; ++q) {
        float rr = __builtin_amdgcn_rcpf(
            1.0f + __builtin_amdgcn_exp2f(aR[ct][q] + bf2f((unsigned short)gR[ct * 4 + q])));
        float zz = __builtin_amdgcn_rcpf(
            1.0f + __builtin_amdgcn_exp2f(aZ[ct][q] + bf2f((unsigned short)gZ[ct * 4 + q])));
        float y = bf2f((unsigned short)gN[ct * 4 + q]) + rr * (aN[ct][q] + cn[ct]);
        float nn = 1.0f - 2.0f * __builtin_amdgcn_rcpf(1.0f + __builtin_amdgcn_exp2f(y));
        float hq = nn + zz * (hv[ct][q] - nn);
        hv[ct][q] = hq;
        hw[SWZ8(4 * g4 + q, j)] = rne_bf16(hq);
      }
    }
    gp += 196608;
    __syncthreads();
  }

  if (t0 + nt < TT) {
#pragma unroll
    for (int ct = 0; ct < 2; ++ct) {
      int j = 32 * w + 16 * ct + i15;
#pragma unroll
      for (int q = 0; q < 4; ++q)
        hchk[(size_t)(b0 + 4 * g4 + q) * 256 + j] = hv[ct][q];
    }
  } else {
#pragma unroll
    for (int ct = 0; ct < 2; ++ct) {
      int j = 32 * w + 16 * ct + i15;
#pragma unroll
      for (int q = 0; q < 4; ++q) hfin[4 * g4 + q][j] = hv[ct][q];
    }
    __syncthreads();
#pragma unroll
    for (int rr = 0; rr < 2; ++rr) {
      int r = 2 * w + rr;
      float s = 0.0f;
#pragma unroll
      for (int k = 0; k < 4; ++k) {
        int col = l + 64 * k;
        s += hfin[r][col] * Wout[col];
      }
#pragma unroll
      for (int off = 32; off > 0; off >>= 1) s += __shfl_xor(s, off, 64);
      if (l == 0) out[b0 + r] = sigm(s + bout[0]);
    }
  }
}

// ---------------- Fused fallback (used only if ws too small) ------------
__global__ __launch_bounds__(1024, 1) void gru_fused_legacy(
    const float* __restrict__ x, const float* __restrict__ Wih,
    const float* __restrict__ Whh, const float* __restrict__ bih,
    const float* __restrict__ bhh, const float* __restrict__ Wout,
    const float* __restrict__ bout, float* __restrict__ out) {
  __shared__ unsigned short hbuf[2][16 * 256];
  __shared__ unsigned short xbuf[2][16 * 256];
  __shared__ float hfin[16][256];
  int tid = threadIdx.x, lane = tid & 63, w = tid >> 6;
  int i15 = lane & 15, g4 = lane >> 4;
  int b0 = blockIdx.x * 16;
  int j = 16 * w + i15;

  short8 whh0[8], whh1[8], whh2[8], wih0[8], wih1[8], wih2[8];
#pragma unroll
  for (int c = 0; c < 8; ++c) {
    int ko = c * 32 + g4 * 8;
    whh0[c] = ldw8(Whh + (size_t)j * 256 + ko);
    whh1[c] = ldw8(Whh + (size_t)(256 + j) * 256 + ko);
    whh2[c] = ldw8(Whh + (size_t)(512 + j) * 256 + ko);
    wih0[c] = ldw8(Wih + (size_t)j * 256 + ko);
    wih1[c] = ldw8(Wih + (size_t)(256 + j) * 256 + ko);
    wih2[c] = ldw8(Wih + (size_t)(512 + j) * 256 + ko);
  }
  float bias_r = bih[j] + bhh[j];
  float bias_z = bih[256 + j] + bhh[256 + j];
  float bihn = bih[512 + j], bhhn = bhh[512 + j];

  f32x4 h = {0, 0, 0, 0};
  for (int idx = tid; idx < 16 * 256; idx += 1024) hbuf[0][idx] = 0;
  {
    int m = tid >> 6, k0 = (tid & 63) << 2;
    float4 v = *reinterpret_cast<const float4*>(x + (size_t)b0 * II + m * 256 + k0);
    ushort4 b;
    b.x = rne_bf16(v.x); b.y = rne_bf16(v.y);
    b.z = rne_bf16(v.z); b.w = rne_bf16(v.w);
    *reinterpret_cast<ushort4*>(&xbuf[0][SWZ(m, k0)]) = b;
  }
  __syncthreads();

  for (int lt = 0; lt < TT; ++lt) {
    int cur = lt & 1, nxt = cur ^ 1;
    short8 ah[8], axf[8];
#pragma unroll
    for (int c = 0; c < 8; ++c) {
      int m = lane & 15, k0 = c * 32 + g4 * 8;
      ah[c] = *reinterpret_cast<const short8*>(&hbuf[cur][SWZ(m, k0)]);
      axf[c] = *reinterpret_cast<const short8*>(&xbuf[cur][SWZ(m, k0)]);
    }
    f32x4 gr = {0, 0, 0, 0}, gz = {0, 0, 0, 0}, gn = {0, 0, 0, 0};
    f32x4 ar = {0, 0, 0, 0}, az = {0, 0, 0, 0}, an = {0, 0, 0, 0};
#pragma unroll
    for (int c = 0; c < 8; ++c) {
      gr = mfma16(axf[c], wih0[c], gr);
      gz = mfma16(axf[c], wih1[c], gz);
      gn = mfma16(axf[c], wih2[c], gn);
    }
    if (lt + 1 < TT) {
      int m = tid >> 6, k0 = (tid & 63) << 2;
      float4 v = *reinterpret_cast<const float4*>(
          x + ((size_t)(lt + 1) * BB + b0) * II + m * 256 + k0);
      ushort4 b;
      b.x = rne_bf16(v.x); b.y = rne_bf16(v.y);
      b.z = rne_bf16(v.z); b.w = rne_bf16(v.w);
      *reinterpret_cast<ushort4*>(&xbuf[nxt][SWZ(m, k0)]) = b;
    }
#pragma unroll
    for (int c = 0; c < 8; ++c) {
      ar = mfma16(ah[c], whh0[c], ar);
      az = mfma16(ah[c], whh1[c], az);
      an = mfma16(ah[c], whh2[c], an);
    }
#pragma unroll
    for (int q = 0; q < 4; ++q) {
      float r = sigm(ar[q] + gr[q] + bias_r);
      float zz = sigm(az[q] + gz[q] + bias_z);
      float nn = tanhfast(gn[q] + bihn + r * (an[q] + bhhn));
      float hq = (1.0f - zz) * nn + zz * h[q];
      h[q] = hq;
      hbuf[nxt][SWZ(g4 * 4 + q, j)] = rne_bf16(hq);
    }
    __syncthreads();
  }
#pragma unroll
  for (int q = 0; q < 4; ++q) hfin[g4 * 4 + q][j] = h[q];
  __syncthreads();
  float s = 0.0f;
#pragma unroll
  for (int i = 0; i < 4; ++i) {
    int k = lane + 64 * i;
    s += hfin[w][k] * Wout[k];
  }
#pragma unroll
  for (int off = 32; off > 0; off >>= 1) s += __shfl_xor(s, off, 64);
  if (lane == 0) out[b0 + w] = sigm(s + bout[0]);
}

extern "C" void kernel_launch(void* const* d_in, const int* in_sizes, int n_in,
                              void* d_out, int out_size, void* d_ws, size_t ws_size,
                              hipStream_t stream) {
  const float* x    = (const float*)d_in[0];
  const float* Wih  = (const float*)d_in[1];
  const float* Whh  = (const float*)d_in[2];
  const float* bih  = (const float*)d_in[3];
  const float* bhh  = (const float*)d_in[4];
  const float* Wout = (const float*)d_in[5];
  const float* bout = (const float*)d_in[6];
  float* out = (float*)d_out;

  const size_t HBYTES = (size_t)BB * HH * sizeof(float);  // 256 KB h checkpoint
  const size_t STEP_BYTES = (size_t)16 * 512 * 48;        // 384 KB gi per step
  size_t gi_cap = ws_size > HBYTES ? ws_size - HBYTES : 0;
  long tc = (long)(gi_cap / STEP_BYTES);
  if (tc > TT) tc = TT;

  if (tc >= 32) {
    float* hchk = (float*)d_ws;
    unsigned short* gi = (unsigned short*)((char*)d_ws + HBYTES);
    for (int t0 = 0; t0 < TT; t0 += (int)tc) {
      int nt = (TT - t0) < (int)tc ? (TT - t0) : (int)tc;
      gi_gemm7<<<dim3(256), dim3(512), 0, stream>>>(
          x + (size_t)t0 * BB * II, Wih, bih, bhh, gi, nt * 16);
      gru_step6<<<dim3(16), dim3(512), 0, stream>>>(
          Whh, bhh, Wout, bout, gi, hchk, out, t0, nt);
    }
  } else {
    gru_fused_legacy<<<dim3(16), dim3(1024), 0, stream>>>(
        x, Wih, Whh, bih, bhh, Wout, bout, out);
  }
}